// Round 8
// baseline (359.204 us; speedup 1.0000x reference)
//
#include <hip/hip_runtime.h>
#include <math.h>

// Problem constants
#define NVEC   65536      // B*H*W
#define CDIM   64
#define KBOOK  1024
#define NTOT   4194304    // B*C*H*W
#define NCHUNK 4
#define KC     (KBOOK / NCHUNK)   // 256
#define MARGIN 1.5e-4f

typedef __attribute__((ext_vector_type(8))) short short8;   // 8 bf16
typedef __attribute__((ext_vector_type(4))) float f32x4;

// ---------------- workspace layout (1.84 MB) ----------------
#define WS_FINALIDX 0         // int[65536]
#define WS_KEYSA    262144    // u64[65536]
#define WS_KEYSB    786432    // u64[65536]
#define WS_BHI      1310720   // ushort[1024*64]
#define WS_BLO      1441792   // ushort[1024*64]
#define WS_SE       1572864   // float[1024]
#define WS_HIST     1576960   // int[1024]
#define WS_RLIST    1581056   // int[65536]
#define WS_RCOUNT   1843200   // int

__device__ __forceinline__ unsigned short f32_to_bf16_rne(float x) {
    unsigned int u = __float_as_uint(x);
    return (unsigned short)((u + 0x7fffu + ((u >> 16) & 1u)) >> 16);
}
__device__ __forceinline__ float bf16_to_f32(unsigned short b) {
    return __uint_as_float(((unsigned int)b) << 16);
}
__device__ __forceinline__ unsigned long long packKey(float f, unsigned int idx) {
    unsigned int o = __float_as_uint(f);
    o = (o & 0x80000000u) ? ~o : (o | 0x80000000u);
    return ((unsigned long long)o << 32) | idx;
}
__device__ __forceinline__ float unpackVal(unsigned long long k) {
    unsigned int o = (unsigned int)(k >> 32);
    return __uint_as_float((o & 0x80000000u) ? (o & 0x7fffffffu) : ~o);
}

// prep: init keys/hist/count; convert codebook to bf16 split of (-2e); exact se
__global__ void prep_kernel(const float* __restrict__ cb, char* __restrict__ ws) {
    unsigned long long* keysA = (unsigned long long*)(ws + WS_KEYSA);
    unsigned long long* keysB = (unsigned long long*)(ws + WS_KEYSB);
    unsigned short* bhi = (unsigned short*)(ws + WS_BHI);
    unsigned short* blo = (unsigned short*)(ws + WS_BLO);
    float* se = (float*)(ws + WS_SE);
    int* hist = (int*)(ws + WS_HIST);
    int* rcount = (int*)(ws + WS_RCOUNT);

    int t = blockIdx.x * 256 + threadIdx.x;   // grid 256 -> t in [0, NVEC)
    keysA[t] = 0xFFFFFFFFFFFFFFFFull;
    keysB[t] = 0xFFFFFFFFFFFFFFFFull;
    if (t == 0) *rcount = 0;
    if (t < KBOOK) {
        hist[t] = 0;
        const float* row = cb + t * CDIM;
        // exact numpy pairwise 8-acc se
        float r[8];
#pragma unroll
        for (int j = 0; j < 8; ++j) r[j] = __fmul_rn(row[j], row[j]);
#pragma unroll
        for (int i = 8; i < 64; i += 8)
#pragma unroll
            for (int j = 0; j < 8; ++j) r[j] = __fadd_rn(r[j], __fmul_rn(row[i + j], row[i + j]));
        se[t] = __fadd_rn(__fadd_rn(__fadd_rn(r[0], r[1]), __fadd_rn(r[2], r[3])),
                          __fadd_rn(__fadd_rn(r[4], r[5]), __fadd_rn(r[6], r[7])));
        // bf16 split of b = -2e
#pragma unroll 8
        for (int c = 0; c < CDIM; ++c) {
            float v = -2.0f * row[c];
            unsigned short hi = f32_to_bf16_rne(v);
            unsigned short lo = f32_to_bf16_rne(v - bf16_to_f32(hi));
            bhi[t * CDIM + c] = hi;
            blo[t * CDIM + c] = lo;
        }
    }
}

// screen: s~[n,k] = se_k + x_n . (-2 e_k) via bf16x3 MFMA; per-n top-2 via atomics
__launch_bounds__(256)
__global__ void screen_kernel(const float* __restrict__ z, char* __restrict__ ws) {
    const unsigned short* bhiG = (const unsigned short*)(ws + WS_BHI);
    const unsigned short* bloG = (const unsigned short*)(ws + WS_BLO);
    const float* seG = (const float*)(ws + WS_SE);
    unsigned long long* keysA = (unsigned long long*)(ws + WS_KEYSA);
    unsigned long long* keysB = (unsigned long long*)(ws + WS_KEYSB);

    // row kl: 256 B = 16 groups of 8 bf16. groups 0-7: hi (g=ch*4+quad), 8-15: lo.
    // XOR swizzle g^(kl&7) keeps b128 reads 2-way-conflict-free (free on CDNA4).
    __shared__ unsigned short sB[256 * 128];   // 64 KiB exactly

    const int tid = threadIdx.x;
    const int wave = tid >> 6, lane = tid & 63;
    const int quad = lane >> 4, l15 = lane & 15;
    const int kc0 = blockIdx.y * KC;
    const int nb0 = blockIdx.x * 128 + wave * 32;

    // stage codebook chunk (hi+lo) into LDS
    for (int i = tid; i < 2048; i += 256) {
        const int k = i >> 3, g3 = i & 7;
        const int gsw = (g3 ^ (k & 7)) * 8;
        *(uint4*)&sB[k * 128 + gsw] = *(const uint4*)(bhiG + (kc0 + k) * CDIM + g3 * 8);
        *(uint4*)&sB[k * 128 + 64 + gsw] = *(const uint4*)(bloG + (kc0 + k) * CDIM + g3 * 8);
    }
    __syncthreads();

    // A fragments: lane holds A[m=l15][c=quad*8+j] for 2 n-blocks x 2 c-chunks, hi+lo split
    const int b = nb0 >> 10;
    const int hwb = nb0 & 1023;
    short8 ahi[2][2], alo[2][2];
#pragma unroll
    for (int nb = 0; nb < 2; ++nb) {
        const float* zp = z + (size_t)b * 65536 + hwb + nb * 16 + l15;
#pragma unroll
        for (int ch = 0; ch < 2; ++ch) {
#pragma unroll
            for (int j = 0; j < 8; ++j) {
                float v = zp[(ch * 32 + quad * 8 + j) * 1024];
                unsigned short hi = f32_to_bf16_rne(v);
                unsigned short lo = f32_to_bf16_rne(v - bf16_to_f32(hi));
                ahi[nb][ch][j] = (short)hi;
                alo[nb][ch][j] = (short)lo;
            }
        }
    }

    float m1[8], m2[8];
    int i1[8];
#pragma unroll
    for (int s = 0; s < 8; ++s) { m1[s] = 3.4e38f; m2[s] = 3.4e38f; i1[s] = 0; }

    for (int t = 0; t < 16; ++t) {
        const int kl = t * 16 + l15;
        const unsigned short* prow = &sB[kl * 128];
        const int sw = (kl & 7);
        short8 bh0 = *(const short8*)&prow[((0 * 4 + quad) ^ sw) * 8];
        short8 bh1 = *(const short8*)&prow[((1 * 4 + quad) ^ sw) * 8];
        short8 bl0 = *(const short8*)&prow[64 + ((0 * 4 + quad) ^ sw) * 8];
        short8 bl1 = *(const short8*)&prow[64 + ((1 * 4 + quad) ^ sw) * 8];
        const float sev = seG[kc0 + kl];
        const int kabs = kc0 + kl;
#pragma unroll
        for (int nb = 0; nb < 2; ++nb) {
            f32x4 acc = {sev, sev, sev, sev};
            acc = __builtin_amdgcn_mfma_f32_16x16x32_bf16(ahi[nb][0], bh0, acc, 0, 0, 0);
            acc = __builtin_amdgcn_mfma_f32_16x16x32_bf16(ahi[nb][1], bh1, acc, 0, 0, 0);
            acc = __builtin_amdgcn_mfma_f32_16x16x32_bf16(ahi[nb][0], bl0, acc, 0, 0, 0);
            acc = __builtin_amdgcn_mfma_f32_16x16x32_bf16(ahi[nb][1], bl1, acc, 0, 0, 0);
            acc = __builtin_amdgcn_mfma_f32_16x16x32_bf16(alo[nb][0], bh0, acc, 0, 0, 0);
            acc = __builtin_amdgcn_mfma_f32_16x16x32_bf16(alo[nb][1], bh1, acc, 0, 0, 0);
#pragma unroll
            for (int reg = 0; reg < 4; ++reg) {
                const int s = nb * 4 + reg;
                const float v = acc[reg];
                m2[s] = fminf(m2[s], fmaxf(v, m1[s]));   // uses OLD m1
                if (v < m1[s]) i1[s] = kabs;
                m1[s] = fminf(m1[s], v);
            }
        }
    }

    // cross-lane top-2 merge within each quad (16 lanes share the same rows)
#pragma unroll
    for (int s = 0; s < 8; ++s) {
        float a1 = m1[s], a2 = m2[s];
        int ai = i1[s];
#pragma unroll
        for (int off = 1; off < 16; off <<= 1) {
            float b1 = __shfl_xor(a1, off);
            float b2 = __shfl_xor(a2, off);
            int bi = __shfl_xor(ai, off);
            bool bwin = (b1 < a1) || (b1 == a1 && bi < ai);
            float lose1 = bwin ? a1 : b1;
            a2 = fminf(fminf(a2, b2), lose1);
            a1 = bwin ? b1 : a1;
            ai = bwin ? bi : ai;
        }
        if (l15 == 0) {
            const int n = nb0 + (s >> 2) * 16 + quad * 4 + (s & 3);
            // DISPLACED-KEY protocol (round-7 bug: this was missing):
            // push the LOSER of the keysA min1 contest into keysB, plus chunk min2.
            // => keysB ends as the exact global 2nd-smallest score (multiset arg:
            // every inserted min1-key except the final winner is displaced once).
            const unsigned long long k1 = packKey(a1, (unsigned int)ai);
            const unsigned long long old = atomicMin(&keysA[n], k1);
            atomicMin(&keysB[n], (old < k1) ? k1 : old);
            atomicMin(&keysB[n], packKey(a2, 0xFFFFFFFFu));
        }
    }
}

// merge: min2-min1 > M  =>  screening argmin == bit-exact numpy argmin
// (numpy-chain reorder slack ~1.5e-5 << M/2); else exact repair.
__global__ void merge_kernel(char* __restrict__ ws) {
    const unsigned long long* keysA = (const unsigned long long*)(ws + WS_KEYSA);
    const unsigned long long* keysB = (const unsigned long long*)(ws + WS_KEYSB);
    int* finalIdx = (int*)(ws + WS_FINALIDX);
    int* rlist = (int*)(ws + WS_RLIST);
    int* rcount = (int*)(ws + WS_RCOUNT);
    const int n = blockIdx.x * 256 + threadIdx.x;
    const unsigned long long ka = keysA[n];
    const float m1 = unpackVal(ka);
    const float m2 = unpackVal(keysB[n]);
    if (m2 - m1 <= MARGIN) {
        rlist[atomicAdd(rcount, 1)] = n;
    } else {
        finalIdx[n] = (int)(ka & 0xFFFFFFFFu);
    }
}

// repair: bit-exact numpy chain for ambiguous n. wave-per-n, k across lanes.
__launch_bounds__(256)
__global__ void repair_kernel(const float* __restrict__ z, const float* __restrict__ cb,
                              char* __restrict__ ws) {
    const float* se = (const float*)(ws + WS_SE);
    const int* rlist = (const int*)(ws + WS_RLIST);
    const int* rcount = (const int*)(ws + WS_RCOUNT);
    int* finalIdx = (int*)(ws + WS_FINALIDX);

    __shared__ float zrow[4][64];
    const int wave = threadIdx.x >> 6, lane = threadIdx.x & 63;
    const int cnt = *rcount;

    for (int item = blockIdx.x * 4 + wave; item < cnt; item += 4096) {
        const int n = rlist[item];
        const int b = n >> 10, hw = n & 1023;
        zrow[wave][lane] = z[(size_t)b * 65536 + lane * 1024 + hw];
        // same-wave LDS write->read: waitcnt orders DS ops within the wave
        __builtin_amdgcn_s_waitcnt(0);   // lgkmcnt(0)+vmcnt(0)

        // exact pairwise 8-acc sx (c ascending; float4 groups preserve order)
        float r[8];
        {
            float4 q0 = *(float4*)&zrow[wave][0];
            float4 q1 = *(float4*)&zrow[wave][4];
            r[0] = __fmul_rn(q0.x, q0.x); r[1] = __fmul_rn(q0.y, q0.y);
            r[2] = __fmul_rn(q0.z, q0.z); r[3] = __fmul_rn(q0.w, q0.w);
            r[4] = __fmul_rn(q1.x, q1.x); r[5] = __fmul_rn(q1.y, q1.y);
            r[6] = __fmul_rn(q1.z, q1.z); r[7] = __fmul_rn(q1.w, q1.w);
#pragma unroll
            for (int g = 2; g < 16; ++g) {
                float4 q = *(float4*)&zrow[wave][g * 4];
                const int base = (g * 4) & 7;
                r[base + 0] = __fadd_rn(r[base + 0], __fmul_rn(q.x, q.x));
                r[base + 1] = __fadd_rn(r[base + 1], __fmul_rn(q.y, q.y));
                r[base + 2] = __fadd_rn(r[base + 2], __fmul_rn(q.z, q.z));
                r[base + 3] = __fadd_rn(r[base + 3], __fmul_rn(q.w, q.w));
            }
        }
        const float sx = __fadd_rn(__fadd_rn(__fadd_rn(r[0], r[1]), __fadd_rn(r[2], r[3])),
                                   __fadd_rn(__fadd_rn(r[4], r[5]), __fadd_rn(r[6], r[7])));

        unsigned long long bestKey = 0xFFFFFFFFFFFFFFFFull;
        for (int jg = 0; jg < 16; jg += 4) {
            float a0 = 0.f, a1 = 0.f, a2 = 0.f, a3 = 0.f;
            const int k0 = (jg + 0) * 64 + lane, k1 = (jg + 1) * 64 + lane;
            const int k2 = (jg + 2) * 64 + lane, k3 = (jg + 3) * 64 + lane;
            const float* r0 = cb + (size_t)k0 * CDIM;
            const float* r1 = cb + (size_t)k1 * CDIM;
            const float* r2 = cb + (size_t)k2 * CDIM;
            const float* r3 = cb + (size_t)k3 * CDIM;
#pragma unroll
            for (int g = 0; g < 16; ++g) {
                float4 zq = *(float4*)&zrow[wave][g * 4];
                float4 c0 = *(const float4*)(r0 + g * 4);
                float4 c1 = *(const float4*)(r1 + g * 4);
                float4 c2 = *(const float4*)(r2 + g * 4);
                float4 c3 = *(const float4*)(r3 + g * 4);
                float zx;
                zx = zq.x + zq.x; a0 = fmaf(zx, c0.x, a0); a1 = fmaf(zx, c1.x, a1); a2 = fmaf(zx, c2.x, a2); a3 = fmaf(zx, c3.x, a3);
                zx = zq.y + zq.y; a0 = fmaf(zx, c0.y, a0); a1 = fmaf(zx, c1.y, a1); a2 = fmaf(zx, c2.y, a2); a3 = fmaf(zx, c3.y, a3);
                zx = zq.z + zq.z; a0 = fmaf(zx, c0.z, a0); a1 = fmaf(zx, c1.z, a1); a2 = fmaf(zx, c2.z, a2); a3 = fmaf(zx, c3.z, a3);
                zx = zq.w + zq.w; a0 = fmaf(zx, c0.w, a0); a1 = fmaf(zx, c1.w, a1); a2 = fmaf(zx, c2.w, a2); a3 = fmaf(zx, c3.w, a3);
            }
            const float d0 = __fsub_rn(__fadd_rn(sx, se[k0]), a0);
            const float d1 = __fsub_rn(__fadd_rn(sx, se[k1]), a1);
            const float d2 = __fsub_rn(__fadd_rn(sx, se[k2]), a2);
            const float d3 = __fsub_rn(__fadd_rn(sx, se[k3]), a3);
            unsigned long long kk;
            kk = packKey(d0, (unsigned int)k0); bestKey = (kk < bestKey) ? kk : bestKey;
            kk = packKey(d1, (unsigned int)k1); bestKey = (kk < bestKey) ? kk : bestKey;
            kk = packKey(d2, (unsigned int)k2); bestKey = (kk < bestKey) ? kk : bestKey;
            kk = packKey(d3, (unsigned int)k3); bestKey = (kk < bestKey) ? kk : bestKey;
        }
#pragma unroll
        for (int off = 32; off > 0; off >>= 1) {
            unsigned long long ok = __shfl_xor(bestKey, off);
            bestKey = (ok < bestKey) ? ok : bestKey;
        }
        if (lane == 0) finalIdx[n] = (int)(bestKey & 0xFFFFFFFFu);
    }
}

// scatter + hist + indices-as-float fused
__global__ void scatterhist_kernel(const float* __restrict__ z, const float* __restrict__ cb,
                                   char* __restrict__ ws, float* __restrict__ out) {
    const int* finalIdx = (const int*)(ws + WS_FINALIDX);
    int* hist = (int*)(ws + WS_HIST);
    __shared__ int lh[KBOOK];
    const bool doHist = (blockIdx.x & 63) == 0;   // block spans one (b,c); c==0 blocks
    if (doHist) {
        for (int i = threadIdx.x; i < KBOOK; i += 256) lh[i] = 0;
        __syncthreads();
    }
    const int o = (blockIdx.x * 256 + threadIdx.x) * 4;
    const int b = o >> 16, c = (o >> 10) & 63, hw = o & 1023;
    const int n = (b << 10) | hw;
    int kk[4];
    float q[4];
#pragma unroll
    for (int j = 0; j < 4; ++j) {
        kk[j] = finalIdx[n + j];
        q[j] = cb[kk[j] * CDIM + c];
    }
    const float4 zv = *(const float4*)(z + o);
    *(float4*)(out + o) = make_float4(q[0], q[1], q[2], q[3]);
    float4 st;
    st.x = __fadd_rn(zv.x, __fsub_rn(q[0], zv.x));
    st.y = __fadd_rn(zv.y, __fsub_rn(q[1], zv.y));
    st.z = __fadd_rn(zv.z, __fsub_rn(q[2], zv.z));
    st.w = __fadd_rn(zv.w, __fsub_rn(q[3], zv.w));
    *(float4*)(out + NTOT + o) = st;
    if (doHist) {
        float* outIdxF = out + 2 * NTOT;
#pragma unroll
        for (int j = 0; j < 4; ++j) {
            outIdxF[n + j] = (float)kk[j];
            atomicAdd(&lh[kk[j]], 1);
        }
        __syncthreads();
        for (int i = threadIdx.x; i < KBOOK; i += 256)
            if (lh[i]) atomicAdd(&hist[i], lh[i]);
    }
}

__global__ void perp_kernel(const char* __restrict__ ws, float* __restrict__ out) {
    const int* hist = (const int*)(ws + WS_HIST);
    __shared__ double partial[16];
    const int t = threadIdx.x;  // 1024 threads
    const int c = hist[t];
    double term = 0.0;
    if (c > 0) { double p = (double)c / (double)NVEC; term = p * log(p); }
    for (int off = 32; off > 0; off >>= 1) term += __shfl_down(term, off);
    if ((t & 63) == 0) partial[t >> 6] = term;
    __syncthreads();
    if (t == 0) {
        double s = 0.0;
        for (int i = 0; i < 16; ++i) s += partial[i];
        out[2 * NTOT + NVEC] = (float)exp(-s);
    }
}

extern "C" void kernel_launch(void* const* d_in, const int* in_sizes, int n_in,
                              void* d_out, int out_size, void* d_ws, size_t ws_size,
                              hipStream_t stream) {
    const float* z  = (const float*)d_in[0];   // [64,64,32,32]
    const float* cb = (const float*)d_in[1];   // [1024,64]
    float* out = (float*)d_out;
    char* ws = (char*)d_ws;

    prep_kernel<<<256, 256, 0, stream>>>(cb, ws);
    dim3 sg(NVEC / 128, NCHUNK);
    screen_kernel<<<sg, 256, 0, stream>>>(z, ws);
    merge_kernel<<<256, 256, 0, stream>>>(ws);
    repair_kernel<<<1024, 256, 0, stream>>>(z, cb, ws);
    scatterhist_kernel<<<NTOT / 1024, 256, 0, stream>>>(z, cb, ws, out);
    perp_kernel<<<1, 1024, 0, stream>>>(ws, out);
}